// Round 4
// baseline (19305.365 us; speedup 1.0000x reference)
//
#include <hip/hip_runtime.h>
#include <stdint.h>

#define BATCH 64
#define TSEQ  512
#define INDIM 256
#define HDIM  512
#define GDIM  2048   // 4*H
#define NCLS  1000
#define TCH   64               // time-chunk for xg staging
#define NCHUNK (TSEQ / TCH)    // 8

// ---------------- workspace layout (bytes) ----------------
// h   : [64][512][512] f32 = 64 MB   (in-place across layers, chunk by chunk)
// xg  : [64][64][2048] f32 = 32 MB   (one chunk)
// c   : [64][512]      f32 = 128 KB  (cell state across chunk launches)
// bar : 24 launches x 4 groups x 64 arrival slots (dword each)
#define H_OFF   0UL
#define XG_OFF  67108864UL
#define C_OFF   (XG_OFF + 33554432UL)
#define BAR_OFF (C_OFF + 131072UL)
#define BAR_BYTES 24576UL
#define WS_NEED (BAR_OFF + BAR_BYTES)

// ---------------- recurrence LDS layout (floats) ----------------
#define W_LDS_F   (512 * 32)       // w_lds[k][32 rows], 64 KB
#define H_STR     19               // stride 19: transpose stores 2-way (free), reads broadcast
#define H_LDS_F   (512 * H_STR)
#define RED_STR   18               // 2-way on write and read
#define RED_F     (4 * 32 * RED_STR)
#define C_F       128
#define REC_F     (W_LDS_F + H_LDS_F + RED_F + C_F)

__device__ __forceinline__ float sigf(float x) {
    return 1.f / (1.f + __expf(-x));
}
__device__ __forceinline__ float tanh_fast(float x) {
    x = fminf(fmaxf(x, -15.f), 15.f);
    const float e = __expf(2.f * x);
    return (e - 1.f) / (e + 1.f);
}

// =====================================================================
// GEMM (one time-chunk): out[m][n] = A_row(m)[:] . W[n][:] + bih[n]+bhh[n]
// m = b*TCH + t_local ; A_row = A + (b*T_A + t0 + t_local)*K
// 128x128 tile, BK=16, 256 threads, 8x8 per thread.  M = 4096.
// =====================================================================
__global__ __launch_bounds__(256) void gemm_xg(
        const float* __restrict__ A, const float* __restrict__ W,
        const float* __restrict__ bih, const float* __restrict__ bhh,
        float* __restrict__ out, int K, int T_A, int t0)
{
    __shared__ float As[16][132];
    __shared__ float Bs[16][132];
    const int n0 = blockIdx.x << 7;
    const int m0 = blockIdx.y << 7;
    const int tid = threadIdx.x;
    const int tm = tid & 15, tn = tid >> 4;
    float acc[8][8] = {};
    const int nch = K >> 4;
    for (int c = 0; c < nch; c++) {
        const int k0 = c << 4;
        #pragma unroll
        for (int i = 0; i < 2; i++) {
            const int j = tid + (i << 8);     // 0..511
            const int r = j >> 2;             // row 0..127
            const int kq = (j & 3) << 2;      // 0,4,8,12
            const int mr = m0 + r;
            const float* arow = A + ((size_t)(mr >> 6) * T_A + t0 + (mr & 63)) * K;
            const float4 av = *(const float4*)&arow[k0 + kq];
            As[kq + 0][r] = av.x; As[kq + 1][r] = av.y;
            As[kq + 2][r] = av.z; As[kq + 3][r] = av.w;
            const float4 bv = *(const float4*)&W[(size_t)(n0 + r) * K + k0 + kq];
            Bs[kq + 0][r] = bv.x; Bs[kq + 1][r] = bv.y;
            Bs[kq + 2][r] = bv.z; Bs[kq + 3][r] = bv.w;
        }
        __syncthreads();
        #pragma unroll
        for (int k = 0; k < 16; k++) {
            float a[8], b[8];
            *(float4*)&a[0] = *(const float4*)&As[k][tm << 3];
            *(float4*)&a[4] = *(const float4*)&As[k][(tm << 3) + 4];
            *(float4*)&b[0] = *(const float4*)&Bs[k][tn << 3];
            *(float4*)&b[4] = *(const float4*)&Bs[k][(tn << 3) + 4];
            #pragma unroll
            for (int i = 0; i < 8; i++)
                #pragma unroll
                for (int jj = 0; jj < 8; jj++)
                    acc[i][jj] = fmaf(a[i], b[jj], acc[i][jj]);
        }
        __syncthreads();
    }
    #pragma unroll
    for (int i = 0; i < 8; i++) {
        const int m = m0 + (tm << 3) + i;
        float* orow = out + (size_t)m * GDIM + n0 + (tn << 3);
        #pragma unroll
        for (int jj = 0; jj < 8; jj++) {
            const int n = n0 + (tn << 3) + jj;
            orow[jj] = acc[i][jj] + bih[n] + bhh[n];
        }
    }
}

// =====================================================================
// Persistent LSTM recurrence, one layer x one time-chunk (TCH steps).
// grid = 256 WGs x 256 thr.  WG w: group g=w&3 (16 batches), slice s=w>>2
// (8 h-units -> 32 gate rows, W_hh slice LDS-resident).
// Barrier: RMW-free.  Arrival = release STORE of (t+1) into arr[g][s]
// (64 independent dwords, no atomic serialization).  Wait = each WG's
// wave 0 polls all 64 slots with ONE coalesced 64-lane load (lane l
// watches slot l, divergent spin).  No master, no flag hop.
// =====================================================================
__global__ __launch_bounds__(256, 1) void lstm_rec(
        const float* __restrict__ Whh,   // [2048][512]
        const float* __restrict__ xg,    // [64][TCH][2048] (chunk)
        float* __restrict__ hout,        // [64][512][512]
        float* __restrict__ cglob,       // [64][512]
        uint32_t* __restrict__ bar,      // this launch: arr[g][64] slots, g-stride 64
        int t0)                          // global start step of chunk
{
    __shared__ float smem[REC_F];
    float* w_lds = smem;                  // [512][32]
    float* h_lds = w_lds + W_LDS_F;       // [512][19]
    float* red   = h_lds + H_LDS_F;       // [4][32][18]
    float* c_st  = red + RED_F;           // [128]

    const int tid = threadIdx.x;
    const int w   = blockIdx.x;
    const int g   = w & 3;
    const int s   = w >> 2;
    uint32_t* arr = bar + g * 64;         // this group's 64 arrival slots

    // ---- stage W_hh slice: LDS banks = r (2-way, free)
    {
        const int r  = tid & 31;          // 0..31
        const int kk = tid >> 5;          // 0..7
        const int grow = ((r >> 3) * HDIM) + (s << 3) + (r & 7);
        const float* wr = Whh + (size_t)grow * HDIM;
        for (int k0 = 0; k0 < HDIM; k0 += 8)
            w_lds[(k0 + kk) * 32 + r] = wr[k0 + kk];
    }
    if (t0 == 0)
        for (int i = tid; i < H_LDS_F; i += 256) h_lds[i] = 0.f;
    if (tid < C_F) {
        const int b = tid >> 3, u = tid & 7;
        c_st[tid] = (t0 == 0) ? 0.f
                  : cglob[(size_t)((g << 4) + b) * HDIM + (s << 3) + u];
    }
    __syncthreads();

    const int wv   = tid >> 6;
    const int lane = tid & 63;
    const int rq   = lane >> 3;   // rows 4rq..4rq+3
    const int bq   = lane & 7;    // batches 2bq,2bq+1

    // pointwise-thread mapping (tid<128): u = tid&7, b = tid>>3
    const int pu = tid & 7, pb = tid >> 3;
    const size_t xbase = ((size_t)((g << 4) + pb) * TCH) * GDIM + (s << 3) + pu;

    float xr0 = 0.f, xr1 = 0.f, xr2 = 0.f, xr3 = 0.f;
    if (tid < 128) {                   // prefetch xg for t_local=0
        xr0 = xg[xbase];
        xr1 = xg[xbase + 512];
        xr2 = xg[xbase + 1024];
        xr3 = xg[xbase + 1536];
    }

    for (int t = 0; t < TCH; t++) {
        const int tg = t0 + t;         // global step
        // ---- load h_{tg-1} (group batches) into transposed LDS (2-way stores)
        if (tg > 0) {
            const int b = tid >> 4, ut = tid & 15;
            const float* hb = hout + ((size_t)((g << 4) + b) * TSEQ + (tg - 1)) * HDIM;
            #pragma unroll
            for (int i = 0; i < 8; i++) {
                const int u0 = (ut << 2) + (i << 6);
                const float4 hv = *(const float4*)&hb[u0];
                h_lds[(u0 + 0) * H_STR + b] = hv.x;
                h_lds[(u0 + 1) * H_STR + b] = hv.y;
                h_lds[(u0 + 2) * H_STR + b] = hv.z;
                h_lds[(u0 + 3) * H_STR + b] = hv.w;
            }
        }
        __syncthreads();

        // prefetch xg for t+1 (in flight under GEMV)
        float nx0 = xr0, nx1 = xr1, nx2 = xr2, nx3 = xr3;
        if (tid < 128) {
            const size_t xo = xbase + (size_t)((t + 1 < TCH) ? (t + 1) : t) * GDIM;
            nx0 = xg[xo];
            nx1 = xg[xo + 512];
            nx2 = xg[xo + 1024];
            nx3 = xg[xo + 1536];
        }

        // ---- GEMV: wave wv covers k in [128wv, 128wv+128)
        float a00 = 0.f, a01 = 0.f, a10 = 0.f, a11 = 0.f;
        float a20 = 0.f, a21 = 0.f, a30 = 0.f, a31 = 0.f;
        const float* wp = w_lds + ((wv << 7) * 32) + (rq << 2);
        const float* hp = h_lds + ((wv << 7) * H_STR) + (bq << 1);
        #pragma unroll 8
        for (int k = 0; k < 128; k++) {
            const float4 w4 = *(const float4*)wp;
            const float h2x = hp[0], h2y = hp[1];
            wp += 32; hp += H_STR;
            a00 = fmaf(w4.x, h2x, a00); a01 = fmaf(w4.x, h2y, a01);
            a10 = fmaf(w4.y, h2x, a10); a11 = fmaf(w4.y, h2y, a11);
            a20 = fmaf(w4.z, h2x, a20); a21 = fmaf(w4.z, h2y, a21);
            a30 = fmaf(w4.w, h2x, a30); a31 = fmaf(w4.w, h2y, a31);
        }
        {
            float* rp = red + wv * (32 * RED_STR) + (rq << 2) * RED_STR + (bq << 1);
            rp[0]              = a00; rp[1]              = a01;
            rp[RED_STR]        = a10; rp[RED_STR + 1]    = a11;
            rp[2 * RED_STR]    = a20; rp[2 * RED_STR + 1] = a21;
            rp[3 * RED_STR]    = a30; rp[3 * RED_STR + 1] = a31;
        }
        __syncthreads();

        // ---- merged reduce + pointwise + h store (tid<128: u=pu, b=pb)
        if (tid < 128) {
            const int o = pu * RED_STR + pb;
            const int W1 = 32 * RED_STR, W2 = 64 * RED_STR, W3 = 96 * RED_STR;
            const int gi_o = o, gf_o = o + 8 * RED_STR,
                      gg_o = o + 16 * RED_STR, go_o = o + 24 * RED_STR;
            const float vi = red[gi_o] + red[W1 + gi_o] + red[W2 + gi_o] + red[W3 + gi_o] + xr0;
            const float vf = red[gf_o] + red[W1 + gf_o] + red[W2 + gf_o] + red[W3 + gf_o] + xr1;
            const float vg = red[gg_o] + red[W1 + gg_o] + red[W2 + gg_o] + red[W3 + gg_o] + xr2;
            const float vo = red[go_o] + red[W1 + go_o] + red[W2 + go_o] + red[W3 + go_o] + xr3;
            const float gi = sigf(vi);
            const float gf = sigf(vf);
            const float gg = tanh_fast(vg);
            const float go = sigf(vo);
            const float c  = fmaf(gf, c_st[tid], gi * gg);
            c_st[tid] = c;
            const float h = go * tanh_fast(c);
            float* hp_out = hout + ((size_t)((g << 4) + pb) * TSEQ + tg) * HDIM + (s << 3) + pu;
            __hip_atomic_store(hp_out, h, __ATOMIC_RELAXED, __HIP_MEMORY_SCOPE_AGENT);
        }
        xr0 = nx0; xr1 = nx1; xr2 = nx2; xr3 = nx3;

        // ---- RMW-free group barrier (skip after final step: kernel exit syncs)
        if (t < TCH - 1) {
            __syncthreads();           // per-wave vmcnt(0) drain: h stores visible
            if (tid < 64) {
                if (tid == 0)
                    __hip_atomic_store(&arr[s], (uint32_t)(t + 1), __ATOMIC_RELEASE,
                                       __HIP_MEMORY_SCOPE_AGENT);
                // lane l spins on slot l; wave reconverges when all 64 arrived
                while (__hip_atomic_load(&arr[tid], __ATOMIC_RELAXED,
                                         __HIP_MEMORY_SCOPE_AGENT) < (uint32_t)(t + 1))
                    __builtin_amdgcn_s_sleep(1);
                __builtin_amdgcn_fence(__ATOMIC_ACQUIRE, "agent");
            }
            __syncthreads();
        }
    }

    // ---- persist cell state for next chunk
    if (tid < 128) {
        cglob[(size_t)((g << 4) + pb) * HDIM + (s << 3) + pu] = c_st[tid];
    }
}

// =====================================================================
// FC head: out[b][c] = h[b][T-1][:] . W_fc[c][:] + b_fc[c]
// =====================================================================
__global__ __launch_bounds__(256) void fc_head(
        const float* __restrict__ hbase,   // [64][512][512]
        const float* __restrict__ Wfc,     // [1000][512]
        const float* __restrict__ bfc,
        float* __restrict__ out)           // [64][1000]
{
    __shared__ float hs[HDIM];
    const int b = blockIdx.x;
    const float* hb = hbase + ((size_t)b * TSEQ + (TSEQ - 1)) * HDIM;
    for (int i = threadIdx.x; i < HDIM; i += 256) hs[i] = hb[i];
    __syncthreads();
    const int wave = threadIdx.x >> 6, lane = threadIdx.x & 63;
    for (int c = wave; c < NCLS; c += 4) {
        const float* wr = Wfc + (size_t)c * HDIM;
        float s = 0.f;
        for (int k = lane; k < HDIM; k += 64) s = fmaf(hs[k], wr[k], s);
        #pragma unroll
        for (int off = 32; off > 0; off >>= 1) s += __shfl_down(s, off, 64);
        if (lane == 0) out[b * NCLS + c] = s + bfc[c];
    }
}

// =====================================================================
extern "C" void kernel_launch(void* const* d_in, const int* in_sizes, int n_in,
                              void* d_out, int out_size, void* d_ws, size_t ws_size,
                              hipStream_t stream)
{
    (void)in_sizes; (void)n_in; (void)out_size;
    if (ws_size < WS_NEED) return;   // readable failure instead of OOB fault

    const float* x   = (const float*)d_in[0];
    const float* Wih[3] = {(const float*)d_in[1], (const float*)d_in[5], (const float*)d_in[9]};
    const float* Whh[3] = {(const float*)d_in[2], (const float*)d_in[6], (const float*)d_in[10]};
    const float* bih[3] = {(const float*)d_in[3], (const float*)d_in[7], (const float*)d_in[11]};
    const float* bhh[3] = {(const float*)d_in[4], (const float*)d_in[8], (const float*)d_in[12]};
    const float* Wfc = (const float*)d_in[13];
    const float* bfc = (const float*)d_in[14];
    float* out = (float*)d_out;

    char* ws = (char*)d_ws;
    float* h  = (float*)(ws + H_OFF);
    float* xg = (float*)(ws + XG_OFF);
    float* cg = (float*)(ws + C_OFF);
    uint32_t* bar = (uint32_t*)(ws + BAR_OFF);

    hipMemsetAsync(bar, 0, BAR_BYTES, stream);

    const dim3 ggrid(GDIM / 128, (BATCH * TCH) / 128), gblk(256);

    for (int l = 0; l < 3; l++) {
        const float* A   = (l == 0) ? x : h;
        const int    K   = (l == 0) ? INDIM : HDIM;
        for (int c = 0; c < NCHUNK; c++) {
            const int t0 = c * TCH;
            gemm_xg<<<ggrid, gblk, 0, stream>>>(A, Wih[l], bih[l], bhh[l], xg, K, TSEQ, t0);
            uint32_t* bp = bar + (l * NCHUNK + c) * 256;
            lstm_rec<<<dim3(256), gblk, 0, stream>>>(Whh[l], xg, h, cg, bp, t0);
        }
    }
    fc_head<<<dim3(64), gblk, 0, stream>>>(h, Wfc, bfc, out);
}

// Round 6
// 14574.158 us; speedup vs baseline: 1.3246x; 1.3246x over previous
//
#include <hip/hip_runtime.h>
#include <stdint.h>

#define BATCH 64
#define TSEQ  512
#define INDIM 256
#define HDIM  512
#define GDIM  2048   // 4*H
#define NCLS  1000
#define TCH   64               // time-chunk for xg staging
#define NCHUNK (TSEQ / TCH)    // 8

// ---------------- workspace layout (bytes) ----------------
#define H_OFF   0UL
#define XG_OFF  67108864UL
#define C_OFF   (XG_OFF + 33554432UL)
#define BAR_OFF (C_OFF + 131072UL)
#define BAR_BYTES 12288UL
#define WS_NEED (BAR_OFF + BAR_BYTES)

typedef _Float16 f16x8 __attribute__((ext_vector_type(8)));
typedef float    f32x4 __attribute__((ext_vector_type(4)));

// ---------------- recurrence LDS (f16 hi/lo h in MFMA-B layout) ----------------
// hb[oct][b][8] with oct-stride 136 f16 (=17x16B: aligned, 2-way banks max)
#define OCT_STR  136
#define HB_F16   (64 * OCT_STR)     // 8704 f16 = 17408 B per array

__device__ __forceinline__ float sigf(float x) {
    return 1.f / (1.f + __expf(-x));
}
__device__ __forceinline__ float tanh_fast(float x) {
    x = fminf(fmaxf(x, -15.f), 15.f);
    const float e = __expf(2.f * x);
    return (e - 1.f) / (e + 1.f);
}
struct f16pair { _Float16 h, l; };
__device__ __forceinline__ f16pair cvt2(float x) {
    f16pair p;
    p.h = (_Float16)x;
    p.l = (_Float16)(x - (float)p.h);
    return p;
}

// =====================================================================
// GEMM (one time-chunk): out[m][n] = A_row(m)[:] . W[n][:] + bih[n]+bhh[n]
// =====================================================================
__global__ __launch_bounds__(256) void gemm_xg(
        const float* __restrict__ A, const float* __restrict__ W,
        const float* __restrict__ bih, const float* __restrict__ bhh,
        float* __restrict__ out, int K, int T_A, int t0)
{
    __shared__ float As[16][132];
    __shared__ float Bs[16][132];
    const int n0 = blockIdx.x << 7;
    const int m0 = blockIdx.y << 7;
    const int tid = threadIdx.x;
    const int tm = tid & 15, tn = tid >> 4;
    float acc[8][8] = {};
    const int nch = K >> 4;
    for (int c = 0; c < nch; c++) {
        const int k0 = c << 4;
        #pragma unroll
        for (int i = 0; i < 2; i++) {
            const int j = tid + (i << 8);
            const int r = j >> 2;
            const int kq = (j & 3) << 2;
            const int mr = m0 + r;
            const float* arow = A + ((size_t)(mr >> 6) * T_A + t0 + (mr & 63)) * K;
            const float4 av = *(const float4*)&arow[k0 + kq];
            As[kq + 0][r] = av.x; As[kq + 1][r] = av.y;
            As[kq + 2][r] = av.z; As[kq + 3][r] = av.w;
            const float4 bv = *(const float4*)&W[(size_t)(n0 + r) * K + k0 + kq];
            Bs[kq + 0][r] = bv.x; Bs[kq + 1][r] = bv.y;
            Bs[kq + 2][r] = bv.z; Bs[kq + 3][r] = bv.w;
        }
        __syncthreads();
        #pragma unroll
        for (int k = 0; k < 16; k++) {
            float a[8], b[8];
            *(float4*)&a[0] = *(const float4*)&As[k][tm << 3];
            *(float4*)&a[4] = *(const float4*)&As[k][(tm << 3) + 4];
            *(float4*)&b[0] = *(const float4*)&Bs[k][tn << 3];
            *(float4*)&b[4] = *(const float4*)&Bs[k][(tn << 3) + 4];
            #pragma unroll
            for (int i = 0; i < 8; i++)
                #pragma unroll
                for (int jj = 0; jj < 8; jj++)
                    acc[i][jj] = fmaf(a[i], b[jj], acc[i][jj]);
        }
        __syncthreads();
    }
    #pragma unroll
    for (int i = 0; i < 8; i++) {
        const int m = m0 + (tm << 3) + i;
        float* orow = out + (size_t)m * GDIM + n0 + (tn << 3);
        #pragma unroll
        for (int jj = 0; jj < 8; jj++) {
            const int n = n0 + (tn << 3) + jj;
            orow[jj] = acc[i][jj] + bih[n] + bhh[n];
        }
    }
}

// =====================================================================
// Persistent LSTM recurrence (MFMA f16x2), one layer x one chunk.
// grid = 256 WGs x 256 thr.  WG w: group g=w&3 (16 batches), slice s=w>>2
// (8 h-units -> 32 gate rows).  W_hh rows live in REGISTERS as f16 hi/lo
// MFMA A-fragments (loaded once per chunk).  Per step: h_prev (global fp32)
// -> f16 hi/lo LDS in B-layout -> 24 mfma_f32_16x16x32_f16 per wave
// (Wh*hh + Wl*hh + Wh*hl) -> k-reduce -> pointwise -> store + barrier.
// Wave wv: rb=wv&1 (row-tile of 16), kh=wv>>1 (k-half of 256).
// =====================================================================
__global__ __launch_bounds__(256, 1) void lstm_rec(
        const float* __restrict__ Whh,   // [2048][512]
        const float* __restrict__ xg,    // [64][TCH][2048] (chunk)
        float* __restrict__ hout,        // [64][512][512]
        float* __restrict__ cglob,       // [64][512]
        uint32_t* __restrict__ bar,      // cnt[g]=bar[g*16], flag[g]=bar[64+g*16]
        int t0)
{
    __shared__ _Float16 hb_hi[HB_F16];
    __shared__ _Float16 hb_lo[HB_F16];
    __shared__ float red[2 * 64 * 4];       // [rb][lane][4]
    __shared__ float gates_t[16 * 36];      // [batch][row] stride 36
    __shared__ float c_st[128];

    const int tid = threadIdx.x;
    const int w   = blockIdx.x;
    const int g   = w & 3;
    const int s   = w >> 2;
    uint32_t* cnt = bar + g * 16;
    uint32_t* flg = bar + 64 + g * 16;

    const int wv   = tid >> 6;
    const int lane = tid & 63;
    const int rb   = wv & 1;      // row-tile (16 rows)
    const int kh   = wv >> 1;     // k-half (256 k)
    const int m16  = lane & 15;
    const int quad = lane >> 4;

    // ---- A-fragments: W_hh rows in registers, f16 hi/lo (once per chunk)
    // A[m=lane&15][k=quad*8+j], tile kt: k base = kh*256 + kt*32 + quad*8
    f16x8 a_hi[8], a_lo[8];
    {
        const int r    = (rb << 4) + m16;                       // row 0..31
        const int grow = ((r >> 3) * HDIM) + (s << 3) + (r & 7);
        const float* wr = Whh + (size_t)grow * HDIM;
        #pragma unroll
        for (int kt = 0; kt < 8; kt++) {
            const int kb = (kh << 8) + (kt << 5) + (quad << 3);
            const float4 w0 = *(const float4*)&wr[kb];
            const float4 w1 = *(const float4*)&wr[kb + 4];
            f16pair p;
            p = cvt2(w0.x); a_hi[kt][0] = p.h; a_lo[kt][0] = p.l;
            p = cvt2(w0.y); a_hi[kt][1] = p.h; a_lo[kt][1] = p.l;
            p = cvt2(w0.z); a_hi[kt][2] = p.h; a_lo[kt][2] = p.l;
            p = cvt2(w0.w); a_hi[kt][3] = p.h; a_lo[kt][3] = p.l;
            p = cvt2(w1.x); a_hi[kt][4] = p.h; a_lo[kt][4] = p.l;
            p = cvt2(w1.y); a_hi[kt][5] = p.h; a_lo[kt][5] = p.l;
            p = cvt2(w1.z); a_hi[kt][6] = p.h; a_lo[kt][6] = p.l;
            p = cvt2(w1.w); a_hi[kt][7] = p.h; a_lo[kt][7] = p.l;
        }
    }

    if (t0 == 0) {
        for (int i = tid; i < HB_F16; i += 256) {
            hb_hi[i] = (_Float16)0.f;
            hb_lo[i] = (_Float16)0.f;
        }
    }
    const int pu = tid & 7, pb = tid >> 3;   // pointwise mapping (tid<128)
    if (tid < 128) {
        c_st[tid] = (t0 == 0) ? 0.f
                  : cglob[(size_t)((g << 4) + pb) * HDIM + (s << 3) + pu];
    }

    const size_t xbase = ((size_t)((g << 4) + pb) * TCH) * GDIM + (s << 3) + pu;
    float xr0 = 0.f, xr1 = 0.f, xr2 = 0.f, xr3 = 0.f;
    if (tid < 128) {
        xr0 = xg[xbase];
        xr1 = xg[xbase + 512];
        xr2 = xg[xbase + 1024];
        xr3 = xg[xbase + 1536];
    }

    // conversion-phase mapping: batch cb, k-octet selector ck
    const int cb = tid >> 4, ck = tid & 15;

    for (int t = 0; t < TCH; t++) {
        const int tg = t0 + t;

        // ---- h_{tg-1} (global fp32) -> f16 hi/lo LDS in B-layout
        if (tg > 0) {
            const float* hrow = hout + ((size_t)((g << 4) + cb) * TSEQ + (tg - 1)) * HDIM;
            #pragma unroll
            for (int i = 0; i < 4; i++) {
                const int u0 = (ck << 3) + (i << 7);    // octet-aligned k base
                const float4 A0 = *(const float4*)&hrow[u0];
                const float4 A1 = *(const float4*)&hrow[u0 + 4];
                f16x8 hi, lo;
                f16pair p;
                p = cvt2(A0.x); hi[0] = p.h; lo[0] = p.l;
                p = cvt2(A0.y); hi[1] = p.h; lo[1] = p.l;
                p = cvt2(A0.z); hi[2] = p.h; lo[2] = p.l;
                p = cvt2(A0.w); hi[3] = p.h; lo[3] = p.l;
                p = cvt2(A1.x); hi[4] = p.h; lo[4] = p.l;
                p = cvt2(A1.y); hi[5] = p.h; lo[5] = p.l;
                p = cvt2(A1.z); hi[6] = p.h; lo[6] = p.l;
                p = cvt2(A1.w); hi[7] = p.h; lo[7] = p.l;
                const int oct = u0 >> 3;
                *(f16x8*)&hb_hi[oct * OCT_STR + (cb << 3)] = hi;
                *(f16x8*)&hb_lo[oct * OCT_STR + (cb << 3)] = lo;
            }
        }
        __syncthreads();

        // prefetch xg for t+1 (in flight under MFMA)
        float nx0 = xr0, nx1 = xr1, nx2 = xr2, nx3 = xr3;
        if (tid < 128) {
            const size_t xo = xbase + (size_t)((t + 1 < TCH) ? (t + 1) : t) * GDIM;
            nx0 = xg[xo];
            nx1 = xg[xo + 512];
            nx2 = xg[xo + 1024];
            nx3 = xg[xo + 1536];
        }

        // ---- MFMA: wave (rb,kh): 8 k-tiles x 3 split products
        f32x4 acc = {0.f, 0.f, 0.f, 0.f};
        #pragma unroll
        for (int kt = 0; kt < 8; kt++) {
            const int oct = (((kh << 3) + kt) << 2) + quad;
            const f16x8 bh = *(const f16x8*)&hb_hi[oct * OCT_STR + (m16 << 3)];
            const f16x8 bl = *(const f16x8*)&hb_lo[oct * OCT_STR + (m16 << 3)];
            acc = __builtin_amdgcn_mfma_f32_16x16x32_f16(a_hi[kt], bh, acc, 0, 0, 0);
            acc = __builtin_amdgcn_mfma_f32_16x16x32_f16(a_lo[kt], bh, acc, 0, 0, 0);
            acc = __builtin_amdgcn_mfma_f32_16x16x32_f16(a_hi[kt], bl, acc, 0, 0, 0);
        }

        // ---- cross-wave k-reduce (kh=1 -> LDS, kh=0 adds) + gate transpose
        if (kh == 1)
            *(f32x4*)&red[(((rb << 6) + lane) << 2)] = acc;
        __syncthreads();
        if (kh == 0) {
            const f32x4 o = *(const f32x4*)&red[(((rb << 6) + lane) << 2)];
            acc += o;
            // C/D: col(batch)=m16, row=quad*4+reg -> gates_t[batch][rb*16+quad*4+reg]
            *(f32x4*)&gates_t[m16 * 36 + (rb << 4) + (quad << 2)] = acc;
        }
        __syncthreads();

        // ---- pointwise + h store (tid<128: unit pu, batch pb)
        if (tid < 128) {
            const float vi = gates_t[pb * 36 + pu]       + xr0;
            const float vf = gates_t[pb * 36 + 8 + pu]   + xr1;
            const float vg = gates_t[pb * 36 + 16 + pu]  + xr2;
            const float vo = gates_t[pb * 36 + 24 + pu]  + xr3;
            const float gi = sigf(vi);
            const float gf = sigf(vf);
            const float gg = tanh_fast(vg);
            const float go = sigf(vo);
            const float c  = fmaf(gf, c_st[tid], gi * gg);
            c_st[tid] = c;
            const float h = go * tanh_fast(c);
            float* hp_out = hout + ((size_t)((g << 4) + pb) * TSEQ + tg) * HDIM + (s << 3) + pu;
            __hip_atomic_store(hp_out, h, __ATOMIC_RELAXED, __HIP_MEMORY_SCOPE_AGENT);
        }
        xr0 = nx0; xr1 = nx1; xr2 = nx2; xr3 = nx3;

        // ---- flag-release group barrier (skip after final step)
        if (t < TCH - 1) {
            __syncthreads();           // drains vmcnt: h stores visible
            if (tid == 0) {
                __hip_atomic_fetch_add(cnt, 1u, __ATOMIC_RELEASE,
                                       __HIP_MEMORY_SCOPE_AGENT);
                if (s == 0) {          // master WG of group g
                    const uint32_t tgt = 64u * (uint32_t)(t + 1);
                    while (__hip_atomic_load(cnt, __ATOMIC_RELAXED,
                                             __HIP_MEMORY_SCOPE_AGENT) < tgt)
                        __builtin_amdgcn_s_sleep(1);
                    __hip_atomic_store(flg, (uint32_t)(t + 1), __ATOMIC_RELEASE,
                                       __HIP_MEMORY_SCOPE_AGENT);
                }
                while (__hip_atomic_load(flg, __ATOMIC_RELAXED,
                                         __HIP_MEMORY_SCOPE_AGENT) < (uint32_t)(t + 1))
                    __builtin_amdgcn_s_sleep(1);
                __builtin_amdgcn_fence(__ATOMIC_ACQUIRE, "agent");
            }
            __syncthreads();
        }
    }

    // ---- persist cell state for next chunk
    if (tid < 128) {
        cglob[(size_t)((g << 4) + pb) * HDIM + (s << 3) + pu] = c_st[tid];
    }
}

// =====================================================================
// FC head: out[b][c] = h[b][T-1][:] . W_fc[c][:] + b_fc[c]
// =====================================================================
__global__ __launch_bounds__(256) void fc_head(
        const float* __restrict__ hbase,   // [64][512][512]
        const float* __restrict__ Wfc,     // [1000][512]
        const float* __restrict__ bfc,
        float* __restrict__ out)           // [64][1000]
{
    __shared__ float hs[HDIM];
    const int b = blockIdx.x;
    const float* hb = hbase + ((size_t)b * TSEQ + (TSEQ - 1)) * HDIM;
    for (int i = threadIdx.x; i < HDIM; i += 256) hs[i] = hb[i];
    __syncthreads();
    const int wave = threadIdx.x >> 6, lane = threadIdx.x & 63;
    for (int c = wave; c < NCLS; c += 4) {
        const float* wr = Wfc + (size_t)c * HDIM;
        float s = 0.f;
        for (int k = lane; k < HDIM; k += 64) s = fmaf(hs[k], wr[k], s);
        #pragma unroll
        for (int off = 32; off > 0; off >>= 1) s += __shfl_down(s, off, 64);
        if (lane == 0) out[b * NCLS + c] = s + bfc[c];
    }
}

// =====================================================================
extern "C" void kernel_launch(void* const* d_in, const int* in_sizes, int n_in,
                              void* d_out, int out_size, void* d_ws, size_t ws_size,
                              hipStream_t stream)
{
    (void)in_sizes; (void)n_in; (void)out_size;
    if (ws_size < WS_NEED) return;   // readable failure instead of OOB fault

    const float* x   = (const float*)d_in[0];
    const float* Wih[3] = {(const float*)d_in[1], (const float*)d_in[5], (const float*)d_in[9]};
    const float* Whh[3] = {(const float*)d_in[2], (const float*)d_in[6], (const float*)d_in[10]};
    const float* bih[3] = {(const float*)d_in[3], (const float*)d_in[7], (const float*)d_in[11]};
    const float* bhh[3] = {(const float*)d_in[4], (const float*)d_in[8], (const float*)d_in[12]};
    const float* Wfc = (const float*)d_in[13];
    const float* bfc = (const float*)d_in[14];
    float* out = (float*)d_out;

    char* ws = (char*)d_ws;
    float* h  = (float*)(ws + H_OFF);
    float* xg = (float*)(ws + XG_OFF);
    float* cg = (float*)(ws + C_OFF);
    uint32_t* bar = (uint32_t*)(ws + BAR_OFF);

    (void)hipMemsetAsync(bar, 0, BAR_BYTES, stream);

    const dim3 ggrid(GDIM / 128, (BATCH * TCH) / 128), gblk(256);

    for (int l = 0; l < 3; l++) {
        const float* A   = (l == 0) ? x : h;
        const int    K   = (l == 0) ? INDIM : HDIM;
        for (int c = 0; c < NCHUNK; c++) {
            const int t0 = c * TCH;
            gemm_xg<<<ggrid, gblk, 0, stream>>>(A, Wih[l], bih[l], bhh[l], xg, K, TSEQ, t0);
            uint32_t* bp = bar + (l * NCHUNK + c) * 128;
            lstm_rec<<<dim3(256), gblk, 0, stream>>>(Whh[l], xg, h, cg, bp, t0);
        }
    }
    fc_head<<<dim3(64), gblk, 0, stream>>>(h, Wfc, bfc, out);
}

// Round 7
// 10049.255 us; speedup vs baseline: 1.9211x; 1.4503x over previous
//
#include <hip/hip_runtime.h>
#include <stdint.h>

#define BATCH 64
#define TSEQ  512
#define INDIM 256
#define HDIM  512
#define GDIM  2048   // 4*H
#define NCLS  1000
#define TCH   64               // time-chunk for xg staging
#define NCHUNK (TSEQ / TCH)    // 8

// ---------------- workspace layout (bytes) ----------------
#define H_OFF   0UL
#define XG_OFF  67108864UL
#define C_OFF   (XG_OFF + 33554432UL)
#define BAR_OFF (C_OFF + 131072UL)
#define BAR_BYTES 24576UL      // 24 launches x 256 dwords (32-slot arr/group + flag/group)
#define WS_NEED (BAR_OFF + BAR_BYTES)

typedef _Float16 f16x8 __attribute__((ext_vector_type(8)));
typedef float    f32x4 __attribute__((ext_vector_type(4)));

// ---------------- recurrence LDS (f16 hi/lo h in MFMA-B layout) ----------------
// hb[oct][b][8] with oct-stride 136 f16 (=17x16B: aligned, 2-way banks max)
#define OCT_STR  136
#define HB_F16   (64 * OCT_STR)     // 8704 f16 = 17408 B per array

__device__ __forceinline__ float sigf(float x) {
    return 1.f / (1.f + __expf(-x));
}
__device__ __forceinline__ float tanh_fast(float x) {
    x = fminf(fmaxf(x, -15.f), 15.f);
    const float e = __expf(2.f * x);
    return (e - 1.f) / (e + 1.f);
}
struct f16pair { _Float16 h, l; };
__device__ __forceinline__ f16pair cvt2(float x) {
    f16pair p;
    p.h = (_Float16)x;
    p.l = (_Float16)(x - (float)p.h);
    return p;
}

// =====================================================================
// GEMM (one time-chunk): out[m][n] = A_row(m)[:] . W[n][:] + bih[n]+bhh[n]
// =====================================================================
__global__ __launch_bounds__(256) void gemm_xg(
        const float* __restrict__ A, const float* __restrict__ W,
        const float* __restrict__ bih, const float* __restrict__ bhh,
        float* __restrict__ out, int K, int T_A, int t0)
{
    __shared__ float As[16][132];
    __shared__ float Bs[16][132];
    const int n0 = blockIdx.x << 7;
    const int m0 = blockIdx.y << 7;
    const int tid = threadIdx.x;
    const int tm = tid & 15, tn = tid >> 4;
    float acc[8][8] = {};
    const int nch = K >> 4;
    for (int c = 0; c < nch; c++) {
        const int k0 = c << 4;
        #pragma unroll
        for (int i = 0; i < 2; i++) {
            const int j = tid + (i << 8);
            const int r = j >> 2;
            const int kq = (j & 3) << 2;
            const int mr = m0 + r;
            const float* arow = A + ((size_t)(mr >> 6) * T_A + t0 + (mr & 63)) * K;
            const float4 av = *(const float4*)&arow[k0 + kq];
            As[kq + 0][r] = av.x; As[kq + 1][r] = av.y;
            As[kq + 2][r] = av.z; As[kq + 3][r] = av.w;
            const float4 bv = *(const float4*)&W[(size_t)(n0 + r) * K + k0 + kq];
            Bs[kq + 0][r] = bv.x; Bs[kq + 1][r] = bv.y;
            Bs[kq + 2][r] = bv.z; Bs[kq + 3][r] = bv.w;
        }
        __syncthreads();
        #pragma unroll
        for (int k = 0; k < 16; k++) {
            float a[8], b[8];
            *(float4*)&a[0] = *(const float4*)&As[k][tm << 3];
            *(float4*)&a[4] = *(const float4*)&As[k][(tm << 3) + 4];
            *(float4*)&b[0] = *(const float4*)&Bs[k][tn << 3];
            *(float4*)&b[4] = *(const float4*)&Bs[k][(tn << 3) + 4];
            #pragma unroll
            for (int i = 0; i < 8; i++)
                #pragma unroll
                for (int jj = 0; jj < 8; jj++)
                    acc[i][jj] = fmaf(a[i], b[jj], acc[i][jj]);
        }
        __syncthreads();
    }
    #pragma unroll
    for (int i = 0; i < 8; i++) {
        const int m = m0 + (tm << 3) + i;
        float* orow = out + (size_t)m * GDIM + n0 + (tn << 3);
        #pragma unroll
        for (int jj = 0; jj < 8; jj++) {
            const int n = n0 + (tn << 3) + jj;
            orow[jj] = acc[i][jj] + bih[n] + bhh[n];
        }
    }
}

// =====================================================================
// Persistent LSTM recurrence (MFMA f16x2), one layer x one chunk.
// grid = 128 WGs x 256 thr.  WG w: group g=w&3 (16 batches), slice s=w>>2
// (s in [0,32): 16 h-units -> 64 gate rows).  Wave wv = GATE (i,f,g,o).
// Each wave owns full K=512 for its 16 rows: A-frags = 128 VGPRs f16 hi/lo,
// 48 MFMAs/step, NO cross-wave k-reduce.
// Barrier: parallel-store arrival into arr[g][s] (one 128B line/group),
// master WG (s==0) wave 0 polls all 32 slots with one 64-lane load + __all,
// releases flag[g]; everyone polls flag.  No atomic RMW anywhere.
// =====================================================================
__global__ __launch_bounds__(256, 1) void lstm_rec(
        const float* __restrict__ Whh,   // [2048][512]
        const float* __restrict__ xg,    // [64][TCH][2048] (chunk)
        float* __restrict__ hout,        // [64][512][512]
        float* __restrict__ cglob,       // [64][512]
        uint32_t* __restrict__ bar,      // arr[g][32]=bar[g*32+s]; flag[g]=bar[128+g*16]
        int t0)
{
    __shared__ _Float16 hb_hi[HB_F16];
    __shared__ _Float16 hb_lo[HB_F16];
    __shared__ float gates_t[4 * 16 * 17];  // [gate][unit][batch] batch-stride 1, unit-stride 17
    __shared__ float c_st[256];

    const int tid = threadIdx.x;
    const int w   = blockIdx.x;
    const int g   = w & 3;
    const int s   = w >> 2;               // 0..31
    uint32_t* arr = bar + g * 32;
    uint32_t* flg = bar + 128 + g * 16;

    const int wv   = tid >> 6;            // wave = gate
    const int lane = tid & 63;
    const int m16  = lane & 15;           // A-row / B-col index
    const int quad = lane >> 4;

    // ---- A-fragments: W_hh rows (gate wv, units s*16+m16) f16 hi/lo, full K
    f16x8 a_hi[16], a_lo[16];
    {
        const int grow = (wv << 9) + (s << 4) + m16;    // gate*512 + unit
        const float* wr = Whh + (size_t)grow * HDIM;
        #pragma unroll
        for (int kt = 0; kt < 16; kt++) {
            const int kb = (kt << 5) + (quad << 3);
            const float4 w0 = *(const float4*)&wr[kb];
            const float4 w1 = *(const float4*)&wr[kb + 4];
            f16pair p;
            p = cvt2(w0.x); a_hi[kt][0] = p.h; a_lo[kt][0] = p.l;
            p = cvt2(w0.y); a_hi[kt][1] = p.h; a_lo[kt][1] = p.l;
            p = cvt2(w0.z); a_hi[kt][2] = p.h; a_lo[kt][2] = p.l;
            p = cvt2(w0.w); a_hi[kt][3] = p.h; a_lo[kt][3] = p.l;
            p = cvt2(w1.x); a_hi[kt][4] = p.h; a_lo[kt][4] = p.l;
            p = cvt2(w1.y); a_hi[kt][5] = p.h; a_lo[kt][5] = p.l;
            p = cvt2(w1.z); a_hi[kt][6] = p.h; a_lo[kt][6] = p.l;
            p = cvt2(w1.w); a_hi[kt][7] = p.h; a_lo[kt][7] = p.l;
        }
    }

    if (t0 == 0) {
        for (int i = tid; i < HB_F16; i += 256) {
            hb_hi[i] = (_Float16)0.f;
            hb_lo[i] = (_Float16)0.f;
        }
    }

    // pointwise mapping: unit u = tid&15, batch b = tid>>4 (all 256 threads)
    const int pu = tid & 15, pb = tid >> 4;
    c_st[tid] = (t0 == 0) ? 0.f
              : cglob[(size_t)((g << 4) + pb) * HDIM + (s << 4) + pu];

    const size_t xbase0 = ((size_t)((g << 4) + pb) * TCH) * GDIM + (s << 4) + pu;
    float xr0 = xg[xbase0], xr1 = xg[xbase0 + 512],
          xr2 = xg[xbase0 + 1024], xr3 = xg[xbase0 + 1536];

    // conversion-phase mapping: batch cb, k-octet selector ck
    const int cb = tid >> 4, ck = tid & 15;

    for (int t = 0; t < TCH; t++) {
        const int tg = t0 + t;

        // ---- h_{tg-1} (global fp32) -> f16 hi/lo LDS in B-layout
        if (tg > 0) {
            const float* hrow = hout + ((size_t)((g << 4) + cb) * TSEQ + (tg - 1)) * HDIM;
            #pragma unroll
            for (int i = 0; i < 4; i++) {
                const int u0 = (ck << 3) + (i << 7);
                const float4 A0 = *(const float4*)&hrow[u0];
                const float4 A1 = *(const float4*)&hrow[u0 + 4];
                f16x8 hi, lo;
                f16pair p;
                p = cvt2(A0.x); hi[0] = p.h; lo[0] = p.l;
                p = cvt2(A0.y); hi[1] = p.h; lo[1] = p.l;
                p = cvt2(A0.z); hi[2] = p.h; lo[2] = p.l;
                p = cvt2(A0.w); hi[3] = p.h; lo[3] = p.l;
                p = cvt2(A1.x); hi[4] = p.h; lo[4] = p.l;
                p = cvt2(A1.y); hi[5] = p.h; lo[5] = p.l;
                p = cvt2(A1.z); hi[6] = p.h; lo[6] = p.l;
                p = cvt2(A1.w); hi[7] = p.h; lo[7] = p.l;
                const int oct = u0 >> 3;
                *(f16x8*)&hb_hi[oct * OCT_STR + (cb << 3)] = hi;
                *(f16x8*)&hb_lo[oct * OCT_STR + (cb << 3)] = lo;
            }
        }
        __syncthreads();

        // prefetch xg for t+1 (in flight under MFMA)
        const size_t xo = xbase0 + (size_t)((t + 1 < TCH) ? (t + 1) : t) * GDIM;
        const float nx0 = xg[xo];
        const float nx1 = xg[xo + 512];
        const float nx2 = xg[xo + 1024];
        const float nx3 = xg[xo + 1536];

        // ---- MFMA: wave wv (gate), 16 k-tiles x 3 split products
        f32x4 acc = {0.f, 0.f, 0.f, 0.f};
        #pragma unroll
        for (int kt = 0; kt < 16; kt++) {
            const int oct = (kt << 2) + quad;
            const f16x8 bh = *(const f16x8*)&hb_hi[oct * OCT_STR + (m16 << 3)];
            const f16x8 bl = *(const f16x8*)&hb_lo[oct * OCT_STR + (m16 << 3)];
            acc = __builtin_amdgcn_mfma_f32_16x16x32_f16(a_hi[kt], bh, acc, 0, 0, 0);
            acc = __builtin_amdgcn_mfma_f32_16x16x32_f16(a_lo[kt], bh, acc, 0, 0, 0);
            acc = __builtin_amdgcn_mfma_f32_16x16x32_f16(a_hi[kt], bl, acc, 0, 0, 0);
        }
        // C/D: col(batch)=m16, row(unit)=quad*4+reg
        #pragma unroll
        for (int j = 0; j < 4; j++)
            gates_t[wv * 272 + ((quad << 2) + j) * 17 + m16] = acc[j];
        __syncthreads();

        // ---- pointwise + h store (all 256: unit pu, batch pb)
        {
            const float vi = gates_t[pu * 17 + pb]        + xr0;
            const float vf = gates_t[272 + pu * 17 + pb]  + xr1;
            const float vg = gates_t[544 + pu * 17 + pb]  + xr2;
            const float vo = gates_t[816 + pu * 17 + pb]  + xr3;
            const float gi = sigf(vi);
            const float gf = sigf(vf);
            const float gg = tanh_fast(vg);
            const float go = sigf(vo);
            const float c  = fmaf(gf, c_st[tid], gi * gg);
            c_st[tid] = c;
            const float h = go * tanh_fast(c);
            float* hp_out = hout + ((size_t)((g << 4) + pb) * TSEQ + tg) * HDIM + (s << 4) + pu;
            __hip_atomic_store(hp_out, h, __ATOMIC_RELAXED, __HIP_MEMORY_SCOPE_AGENT);
        }
        xr0 = nx0; xr1 = nx1; xr2 = nx2; xr3 = nx3;

        // ---- RMW-free flag barrier (skip after final step: kernel exit syncs)
        if (t < TCH - 1) {
            __syncthreads();           // per-wave vmcnt drain: h stores visible
            if (tid == 0)
                __hip_atomic_store(&arr[s], (uint32_t)(t + 1), __ATOMIC_RELEASE,
                                   __HIP_MEMORY_SCOPE_AGENT);
            if (s == 0 && tid < 64) {  // master WG: wave 0 watches all 32 slots
                while (!__all((int)(__hip_atomic_load(&arr[lane & 31], __ATOMIC_RELAXED,
                                                      __HIP_MEMORY_SCOPE_AGENT)
                                    >= (uint32_t)(t + 1))))
                    __builtin_amdgcn_s_sleep(1);
                if (tid == 0)
                    __hip_atomic_store(flg, (uint32_t)(t + 1), __ATOMIC_RELEASE,
                                       __HIP_MEMORY_SCOPE_AGENT);
            }
            if (tid == 0) {
                while (__hip_atomic_load(flg, __ATOMIC_RELAXED,
                                         __HIP_MEMORY_SCOPE_AGENT) < (uint32_t)(t + 1))
                    __builtin_amdgcn_s_sleep(1);
                __builtin_amdgcn_fence(__ATOMIC_ACQUIRE, "agent");
            }
            __syncthreads();
        }
    }

    // ---- persist cell state for next chunk
    cglob[(size_t)((g << 4) + pb) * HDIM + (s << 4) + pu] = c_st[tid];
}

// =====================================================================
// FC head: out[b][c] = h[b][T-1][:] . W_fc[c][:] + b_fc[c]
// =====================================================================
__global__ __launch_bounds__(256) void fc_head(
        const float* __restrict__ hbase,   // [64][512][512]
        const float* __restrict__ Wfc,     // [1000][512]
        const float* __restrict__ bfc,
        float* __restrict__ out)           // [64][1000]
{
    __shared__ float hs[HDIM];
    const int b = blockIdx.x;
    const float* hb = hbase + ((size_t)b * TSEQ + (TSEQ - 1)) * HDIM;
    for (int i = threadIdx.x; i < HDIM; i += 256) hs[i] = hb[i];
    __syncthreads();
    const int wave = threadIdx.x >> 6, lane = threadIdx.x & 63;
    for (int c = wave; c < NCLS; c += 4) {
        const float* wr = Wfc + (size_t)c * HDIM;
        float s = 0.f;
        for (int k = lane; k < HDIM; k += 64) s = fmaf(hs[k], wr[k], s);
        #pragma unroll
        for (int off = 32; off > 0; off >>= 1) s += __shfl_down(s, off, 64);
        if (lane == 0) out[b * NCLS + c] = s + bfc[c];
    }
}

// =====================================================================
extern "C" void kernel_launch(void* const* d_in, const int* in_sizes, int n_in,
                              void* d_out, int out_size, void* d_ws, size_t ws_size,
                              hipStream_t stream)
{
    (void)in_sizes; (void)n_in; (void)out_size;
    if (ws_size < WS_NEED) return;   // readable failure instead of OOB fault

    const float* x   = (const float*)d_in[0];
    const float* Wih[3] = {(const float*)d_in[1], (const float*)d_in[5], (const float*)d_in[9]};
    const float* Whh[3] = {(const float*)d_in[2], (const float*)d_in[6], (const float*)d_in[10]};
    const float* bih[3] = {(const float*)d_in[3], (const float*)d_in[7], (const float*)d_in[11]};
    const float* bhh[3] = {(const float*)d_in[4], (const float*)d_in[8], (const float*)d_in[12]};
    const float* Wfc = (const float*)d_in[13];
    const float* bfc = (const float*)d_in[14];
    float* out = (float*)d_out;

    char* ws = (char*)d_ws;
    float* h  = (float*)(ws + H_OFF);
    float* xg = (float*)(ws + XG_OFF);
    float* cg = (float*)(ws + C_OFF);
    uint32_t* bar = (uint32_t*)(ws + BAR_OFF);

    (void)hipMemsetAsync(bar, 0, BAR_BYTES, stream);

    const dim3 ggrid(GDIM / 128, (BATCH * TCH) / 128), gblk(256);

    for (int l = 0; l < 3; l++) {
        const float* A   = (l == 0) ? x : h;
        const int    K   = (l == 0) ? INDIM : HDIM;
        for (int c = 0; c < NCHUNK; c++) {
            const int t0 = c * TCH;
            gemm_xg<<<ggrid, gblk, 0, stream>>>(A, Wih[l], bih[l], bhh[l], xg, K, TSEQ, t0);
            uint32_t* bp = bar + (l * NCHUNK + c) * 256;
            lstm_rec<<<dim3(128), gblk, 0, stream>>>(Whh[l], xg, h, cg, bp, t0);
        }
    }
    fc_head<<<dim3(64), gblk, 0, stream>>>(h, Wfc, bfc, out);
}